// Round 1
// baseline (43.205 us; speedup 1.0000x reference)
//
#include <hip/hip_runtime.h>
#include <math.h>

namespace {
constexpr int B  = 16;
constexpr int CH = 4;
constexpr int H  = 512;
constexpr int W  = 512;
constexpr int HID = 8;

// One thread computes 4 consecutive output pixels (all 4 channels) at (b, h, w0..w0+3).
__global__ __launch_bounds__(256) void ca_kernel(
    const float* __restrict__ x,      // [16,4,512,512]
    const float* __restrict__ w1w,    // [8,16]
    const float* __restrict__ w1b,    // [8]
    const float* __restrict__ w2w,    // [4,8]
    const float* __restrict__ noise,  // [16,1,512,512]
    float* __restrict__ out)          // [16,4,512,512]
{
    const int idx = blockIdx.x * 256 + threadIdx.x;
    const int w4 = idx & (W / 4 - 1);        // 0..127 (group of 4 columns)
    const int h  = (idx >> 7) & (H - 1);     // 0..511
    const int b  = idx >> 16;                // 0..15

    const int w0 = w4 << 2;
    const int wl = (w0 - 1) & (W - 1);       // wrapped left column
    const int wr = (w0 + 4) & (W - 1);       // wrapped right column
    const int hm = (h - 1) & (H - 1);        // wrapped row above
    const int hp = (h + 1) & (H - 1);        // wrapped row below

    // hidden pre-activations, one per (hidden unit, pixel)
    float hpre[HID][4];
#pragma unroll
    for (int o = 0; o < HID; ++o) {
        const float bo = w1b[o];             // uniform scalar load
#pragma unroll
        for (int j = 0; j < 4; ++j) hpre[o][j] = bo;
    }

    float xc[CH][4];                         // center pixels (for residual)

#pragma unroll
    for (int c = 0; c < CH; ++c) {
        const float* base = x + (size_t)(b * CH + c) * (H * W);
        const float* rt = base + hm * W;
        const float* rc = base + h  * W;
        const float* rb = base + hp * W;
        const float4 t4 = *(const float4*)(rt + w0);
        const float4 c4 = *(const float4*)(rc + w0);
        const float4 b4 = *(const float4*)(rb + w0);
        // 6-column windows: [w0-1, w0, w0+1, w0+2, w0+3, w0+4] (circular)
        const float t[6]  = { rt[wl], t4.x, t4.y, t4.z, t4.w, rt[wr] };
        const float mm[6] = { rc[wl], c4.x, c4.y, c4.z, c4.w, rc[wr] };
        const float bb[6] = { rb[wl], b4.x, b4.y, b4.z, b4.w, rb[wr] };
        xc[c][0] = c4.x; xc[c][1] = c4.y; xc[c][2] = c4.z; xc[c][3] = c4.w;

#pragma unroll
        for (int j = 0; j < 4; ++j) {
            const float a00 = t[j],  a01 = t[j+1],  a02 = t[j+2];
            const float a10 = mm[j], a11 = mm[j+1], a12 = mm[j+2];
            const float a20 = bb[j], a21 = bb[j+1], a22 = bb[j+2];
            // fixed perception filters (XLA conv = cross-correlation, no flip)
            const float id = a11;
            const float sx = (a02 - a00) + 2.f * (a12 - a10) + (a22 - a20);
            const float sy = (a20 - a00) + 2.f * (a21 - a01) + (a22 - a02);
            const float lp = (a00 + a02 + a20 + a22)
                           + 2.f * (a01 + a10 + a12 + a21) - 12.f * a11;
            // accumulate into all hidden units; w1 row offsets are
            // compile-time constants after unroll -> scalar loads
#pragma unroll
            for (int o = 0; o < HID; ++o) {
                const float* wr1 = w1w + o * 16 + c * 4;
                hpre[o][j] = fmaf(id, wr1[0],
                             fmaf(sx, wr1[1],
                             fmaf(sy, wr1[2],
                             fmaf(lp, wr1[3], hpre[o][j]))));
            }
        }
    }

    // stochastic update mask: floor(U + 0.5), exact np semantics
    const float4 nz = *(const float4*)(noise + ((size_t)b * H + h) * W + w0);
    const float msk[4] = { floorf(nz.x + 0.5f), floorf(nz.y + 0.5f),
                           floorf(nz.z + 0.5f), floorf(nz.w + 0.5f) };

    // relu
#pragma unroll
    for (int o = 0; o < HID; ++o)
#pragma unroll
        for (int j = 0; j < 4; ++j)
            hpre[o][j] = fmaxf(hpre[o][j], 0.f);

    // layer 2 + residual + masked update
#pragma unroll
    for (int c = 0; c < CH; ++c) {
        float d[4] = { 0.f, 0.f, 0.f, 0.f };
#pragma unroll
        for (int o = 0; o < HID; ++o) {
            const float wv = w2w[c * HID + o];   // uniform scalar load
#pragma unroll
            for (int j = 0; j < 4; ++j) d[j] = fmaf(hpre[o][j], wv, d[j]);
        }
        float4 ov;
        ov.x = fmaf(d[0], msk[0], xc[c][0]);
        ov.y = fmaf(d[1], msk[1], xc[c][1]);
        ov.z = fmaf(d[2], msk[2], xc[c][2]);
        ov.w = fmaf(d[3], msk[3], xc[c][3]);
        *(float4*)(out + ((size_t)(b * CH + c) * H + h) * W + w0) = ov;
    }
}
} // namespace

extern "C" void kernel_launch(void* const* d_in, const int* in_sizes, int n_in,
                              void* d_out, int out_size, void* d_ws, size_t ws_size,
                              hipStream_t stream) {
    const float* x     = (const float*)d_in[0];
    const float* w1w   = (const float*)d_in[1];
    const float* w1b   = (const float*)d_in[2];
    const float* w2w   = (const float*)d_in[3];
    const float* noise = (const float*)d_in[4];
    float* out = (float*)d_out;

    const int total_threads = B * H * (W / 4);   // 1,048,576
    ca_kernel<<<total_threads / 256, 256, 0, stream>>>(x, w1w, w1b, w2w, noise, out);
}